// Round 11
// baseline (1182.858 us; speedup 1.0000x reference)
//
#include <hip/hip_runtime.h>

#define HD 512
#define VOC 10000
#define SL 32
#define BA 256
#define BH (BA*HD)

typedef __bf16 b16x8 __attribute__((ext_vector_type(8)));
typedef float f32x4 __attribute__((ext_vector_type(4)));
typedef unsigned u32x4 __attribute__((ext_vector_type(4)));

__device__ __forceinline__ ushort f2bf(float x) {
  unsigned u = __float_as_uint(x);
  u += 0x7fffu + ((u >> 16) & 1u);
  return (ushort)(u >> 16);
}

// ---- LLC write-through (sc0 sc1) accessors ----
__device__ __forceinline__ void stg_sc(void* p, u32x4 v) {
  asm volatile("global_store_dwordx4 %0, %1, off sc0 sc1"
               :: "v"(p), "v"(v) : "memory");
}
__device__ __forceinline__ void stg_sc1(void* p, unsigned v) {
  asm volatile("global_store_dword %0, %1, off sc0 sc1"
               :: "v"(p), "v"(v) : "memory");
}
__device__ __forceinline__ unsigned ldg_sc1(const void* p) {
  unsigned v;
  asm volatile("global_load_dword %0, %1, off sc0 sc1"
               : "=v"(v) : "v"(p) : "memory");
  asm volatile("s_waitcnt vmcnt(0)" ::: "memory");
  return v;
}
__device__ __forceinline__ void vmwait0() {
  asm volatile("s_waitcnt vmcnt(0)" ::: "memory");
  __builtin_amdgcn_sched_barrier(0);
}

// ---------------- merged fp32 -> bf16 converts (out_w | comb_w | attn_w) ----------------
__global__ __launch_bounds__(256) void cvt3_k(
    const float* __restrict__ w_out, ushort* __restrict__ o_out,
    const float* __restrict__ w_comb, ushort* __restrict__ o_comb,
    const float* __restrict__ w_attn, ushort* __restrict__ o_attn) {
  int b = blockIdx.x;
  const float* in; ushort* out; int i; int n4;
  if (b < 5000)      { in = w_out;  out = o_out;  i = b * 256 + threadIdx.x;          n4 = 1280000; }
  else if (b < 5512) { in = w_comb; out = o_comb; i = (b - 5000) * 256 + threadIdx.x; n4 = 131072; }
  else               { in = w_attn; out = o_attn; i = (b - 5512) * 256 + threadIdx.x; n4 = 8192; }
  if (i < n4) {
    float4 v = ((const float4*)in)[i];
    ((ushort4*)out)[i] = make_ushort4(f2bf(v.x), f2bf(v.y), f2bf(v.z), f2bf(v.w));
  }
}

// ---------------- merged embedding gathers ----------------
__global__ __launch_bounds__(64) void gather2_k(
    const float* __restrict__ enc_t, const float* __restrict__ dec_t,
    const int* __restrict__ in_tok, const int* __restrict__ tgt_tok,
    ushort* __restrict__ enc_o, ushort* __restrict__ dec_o) {
  int bid = blockIdx.x;
  int isDec = bid >= SL * BA;
  int row = isDec ? bid - SL * BA : bid;
  int l = row >> 8, b = row & 255;
  int tok = isDec ? ((l == 0) ? 1 : tgt_tok[b * SL + l - 1]) : in_tok[b * SL + l];
  const float* table = isDec ? dec_t : enc_t;
  ushort* out = isDec ? dec_o : enc_o;
  const float4* src = (const float4*)(table + (size_t)tok * HD);
  int t = threadIdx.x;
  float4 v0 = src[t * 2], v1 = src[t * 2 + 1];
  uint4 o;
  o.x = (unsigned)f2bf(v0.x) | ((unsigned)f2bf(v0.y) << 16);
  o.y = (unsigned)f2bf(v0.z) | ((unsigned)f2bf(v0.w) << 16);
  o.z = (unsigned)f2bf(v1.x) | ((unsigned)f2bf(v1.y) << 16);
  o.w = (unsigned)f2bf(v1.z) | ((unsigned)f2bf(v1.w) << 16);
  *(uint4*)(out + (size_t)row * HD + t * 8) = o;
}

// ---------------- merged precompute GEMM: attn_pre + comb_pre ----------------
__global__ __launch_bounds__(256) void gemm2_k(
    const ushort* __restrict__ A,
    const ushort* __restrict__ Wc, const ushort* __restrict__ Wa,
    const float* __restrict__ bc, const float* __restrict__ ba,
    float* __restrict__ outc, float* __restrict__ outa) {
  __shared__ ushort lsA[4][64][8];
  __shared__ ushort lsB[4][64][8];
  __shared__ float ctile[64][68];
  int t = threadIdx.x;
  int lane = t & 63, w = t >> 6;
  int by = blockIdx.y;
  const ushort* W; const float* bias; float* outf; int N, n0, ldc;
  if (by < 8) { W = Wc; bias = bc; outf = outc; N = 512; n0 = by * 64; ldc = 512; }
  else        { W = Wa; bias = ba; outf = outa; N = 32;  n0 = 0;       ldc = 32; }
  int m0 = blockIdx.x * 64;
  f32x4 acc[4] = {};
  int sr = t >> 2, g = t & 3;
  const ushort* Ap = A + (size_t)(m0 + sr) * HD + g * 8;
  int nr = n0 + sr; if (nr > N - 1) nr = N - 1;
  const ushort* Wp = W + (size_t)nr * 1024 + g * 8;
  for (int ks = 0; ks < 16; ++ks) {
    *(uint4*)(&lsA[g][sr][0]) = *(const uint4*)(Ap + ks * 32);
    *(uint4*)(&lsB[g][sr][0]) = *(const uint4*)(Wp + ks * 32);
    __syncthreads();
    int gg = lane >> 4, r = lane & 15;
    b16x8 bf = *(const b16x8*)(&lsB[gg][w * 16 + r][0]);
#pragma unroll
    for (int mi = 0; mi < 4; ++mi) {
      b16x8 af = *(const b16x8*)(&lsA[gg][mi * 16 + r][0]);
      acc[mi] = __builtin_amdgcn_mfma_f32_16x16x32_bf16(af, bf, acc[mi], 0, 0, 0);
    }
    __syncthreads();
  }
  int gg = lane >> 4, cl = lane & 15;
  int tcol = w * 16 + cl;
  int bc2 = n0 + tcol; if (bc2 > N - 1) bc2 = N - 1;
  float bv = bias[bc2];
#pragma unroll
  for (int mi = 0; mi < 4; ++mi)
#pragma unroll
    for (int r = 0; r < 4; ++r)
      ctile[mi * 16 + gg * 4 + r][tcol] = acc[mi][r] + bv;
  __syncthreads();
  int row = t >> 2, q = t & 3;
#pragma unroll
  for (int j = 0; j < 4; ++j) {
    int c = q * 16 + j * 4;
    if (n0 + c + 3 <= N - 1)
      *(float4*)(outf + (size_t)(m0 + row) * ldc + n0 + c) =
          *(const float4*)&ctile[row][c];
  }
}

// ---------------- encW GEMM -> interleaved layout [sl][b][ll][16] ----------------
__global__ __launch_bounds__(256) void gemmW_k(
    const ushort* __restrict__ A, const ushort* __restrict__ W,
    ushort* __restrict__ outI) {
  __shared__ ushort lsA[4][64][8];
  __shared__ ushort lsB[4][64][8];
  __shared__ ushort ctileS[64][64];
  int t = threadIdx.x, lane = t & 63, w = t >> 6;
  int m0 = blockIdx.x * 64, n0 = blockIdx.y * 64;
  f32x4 acc[4] = {};
  int sr = t >> 2, g = t & 3;
  const ushort* Ap = A + (size_t)(m0 + sr) * HD + g * 8;
  const ushort* Wp = W + (size_t)(n0 + sr) * 1024 + 512 + g * 8;
  for (int ks = 0; ks < 16; ++ks) {
    *(uint4*)(&lsA[g][sr][0]) = *(const uint4*)(Ap + ks * 32);
    *(uint4*)(&lsB[g][sr][0]) = *(const uint4*)(Wp + ks * 32);
    __syncthreads();
    int gg = lane >> 4, r = lane & 15;
    b16x8 bf = *(const b16x8*)(&lsB[gg][w * 16 + r][0]);
#pragma unroll
    for (int mi = 0; mi < 4; ++mi) {
      b16x8 af = *(const b16x8*)(&lsA[gg][mi * 16 + r][0]);
      acc[mi] = __builtin_amdgcn_mfma_f32_16x16x32_bf16(af, bf, acc[mi], 0, 0, 0);
    }
    __syncthreads();
  }
  int gg = lane >> 4, cl = lane & 15;
  int tcol = w * 16 + cl;
#pragma unroll
  for (int mi = 0; mi < 4; ++mi)
#pragma unroll
    for (int r = 0; r < 4; ++r)
      ctileS[mi * 16 + gg * 4 + r][tcol] = f2bf(acc[mi][r]);
  __syncthreads();
  int l = m0 >> 8, b0 = m0 & 255;
  int sl_i = t >> 6, tid = t & 63;
  int sl_g = (n0 >> 4) + sl_i;
  ushort* dst = outI + ((((size_t)sl_g * 256 + b0 + tid) * 32) + l) * 16;
  *(uint4*)dst = *(const uint4*)&ctileS[tid][sl_i * 16];
  *(uint4*)(dst + 8) = *(const uint4*)&ctileS[tid][sl_i * 16 + 8];
}

// ---------------- bf16 GEMM 128x128 tile (big output projection) ----------------
__global__ __launch_bounds__(256) void gemmbig_k(
    const ushort* __restrict__ A, const ushort* __restrict__ W,
    int N, const float* __restrict__ bias,
    float* __restrict__ outf, int ldc) {
  __shared__ ushort lsA[4][128][8];
  __shared__ ushort lsB[4][128][8];
  __shared__ float ctile[64][132];
  int t = threadIdx.x, lane = t & 63, w = t >> 6;
  int m0 = blockIdx.x * 128, n0 = blockIdx.y * 128;
  f32x4 acc[8][2] = {};
  int arow = t >> 1, ag = t & 1;
  const ushort* Ap = A + (size_t)(m0 + arow) * HD + ag * 16;
  int nr = n0 + arow; if (nr > N - 1) nr = N - 1;
  const ushort* Wp = W + (size_t)nr * HD + ag * 16;
  for (int ks = 0; ks < 16; ++ks) {
    *(uint4*)(&lsA[ag * 2][arow][0])     = *(const uint4*)(Ap + ks * 32);
    *(uint4*)(&lsA[ag * 2 + 1][arow][0]) = *(const uint4*)(Ap + ks * 32 + 8);
    *(uint4*)(&lsB[ag * 2][arow][0])     = *(const uint4*)(Wp + ks * 32);
    *(uint4*)(&lsB[ag * 2 + 1][arow][0]) = *(const uint4*)(Wp + ks * 32 + 8);
    __syncthreads();
    int gg = lane >> 4, r = lane & 15;
    b16x8 bf0 = *(const b16x8*)(&lsB[gg][w * 32 + r][0]);
    b16x8 bf1 = *(const b16x8*)(&lsB[gg][w * 32 + 16 + r][0]);
#pragma unroll
    for (int mi = 0; mi < 8; ++mi) {
      b16x8 af = *(const b16x8*)(&lsA[gg][mi * 16 + r][0]);
      acc[mi][0] = __builtin_amdgcn_mfma_f32_16x16x32_bf16(af, bf0, acc[mi][0], 0, 0, 0);
      acc[mi][1] = __builtin_amdgcn_mfma_f32_16x16x32_bf16(af, bf1, acc[mi][1], 0, 0, 0);
    }
    __syncthreads();
  }
  int gg = lane >> 4, cl = lane & 15;
#pragma unroll
  for (int half = 0; half < 2; ++half) {
    __syncthreads();
#pragma unroll
    for (int mi = 0; mi < 4; ++mi) {
      int m = half * 4 + mi;
#pragma unroll
      for (int nf = 0; nf < 2; ++nf) {
        int tc = w * 32 + nf * 16 + cl;
        int bc = n0 + tc; if (bc > N - 1) bc = N - 1;
        float bv = bias[bc];
#pragma unroll
        for (int r2 = 0; r2 < 4; ++r2)
          ctile[mi * 16 + gg * 4 + r2][tc] = acc[m][nf][r2] + bv;
      }
    }
    __syncthreads();
    int row = t >> 2, q = t & 3;
#pragma unroll
    for (int j = 0; j < 8; ++j) {
      int c = q * 32 + j * 4;
      if (n0 + c + 3 <= N - 1)
        *(float4*)(outf + (size_t)(m0 + half * 64 + row) * ldc + n0 + c) =
            *(const float4*)&ctile[row][c];
    }
  }
}

// ================= persistent recurrence: 128 blocks x 2 contexts =================
// block (rp = bid&3, sl = bid>>2) serves rg = rp and rg = rp+4 (independent
// pipelines, shared LDS weights). Barrier latency hides under the other
// context's compute. Pure-LLC flags (placement-independent).

__device__ __forceinline__ const ushort* sfrag(const ushort* base, int kh,
                                               int gg, int row) {
  return base + (kh * 16 + (gg >> 1)) * 4096 + row * 16 + (gg & 1) * 8;
}

struct EncArgs {
  const ushort* enc_emb_bf;
  const float* enc_w_ih; const float* enc_w_hh;
  const float* enc_b_ih; const float* enc_b_hh;
  ushort* enc_outs_s;
  ushort* enc_outs_rm;
  float* Hc;
  unsigned* fLLC;            // [8][32*16]
};

struct DecArgs {
  const float* dec_w_ih; const float* dec_w_hh;
  const float* dec_b_ih; const float* dec_b_hh;
  const ushort* attn_w_bf;
  const float* attn_pre;
  const float* comb_pre;
  const ushort* enc_outs_s;
  const ushort* encW;        // interleaved [sl][b][ll][16]
  const float* Hc;
  ushort* H2_s; ushort* H2_rm; ushort* x_s;
  unsigned* fLLC;
};

union DScr {
  float red[2][6][64][4];
  struct { float sS[2][32][33]; float sAW[32][33]; } at;
};

#define BAR_DEFS(fFp)                                                   \
  auto produce = [&](int rg, unsigned val) {                            \
    __syncthreads();                                                    \
    if (w == 0) {                                                       \
      vmwait0();                                                        \
      if (lane == 0) stg_sc1(&(fFp)[rg * 512 + sl * 16], val);          \
    }                                                                   \
  };                                                                    \
  auto await = [&](int rg, unsigned val) {                              \
    if (w == 0) {                                                       \
      for (;;) {                                                        \
        unsigned v = ldg_sc1(&(fFp)[rg * 512 + (lane & 31) * 16]);      \
        if (!__any(v < val)) break;                                     \
        __builtin_amdgcn_s_sleep(1);                                    \
      }                                                                 \
    }                                                                   \
    __syncthreads();                                                    \
  }

#define LOAD_GRU_W32(Wih, Whh)                                          \
  for (int c = w; c < 96; c += 4) {                                     \
    int g = c >> 4, rem = c & 15, kh2 = rem >> 3, ks = rem & 7;         \
    const float* src = (g < 3) ? (Wih) : (Whh);                         \
    int gr = (g % 3) * 512 + sl * 16 + (lane & 15);                     \
    int col = kh2 * 256 + ks * 32 + (lane >> 4) * 8;                    \
    const float4* s4 = (const float4*)(src + (size_t)gr * HD + col);    \
    float4 va = s4[0], vb = s4[1];                                      \
    uint4 o;                                                            \
    o.x = (unsigned)f2bf(va.x) | ((unsigned)f2bf(va.y) << 16);          \
    o.y = (unsigned)f2bf(va.z) | ((unsigned)f2bf(va.w) << 16);          \
    o.z = (unsigned)f2bf(vb.x) | ((unsigned)f2bf(vb.y) << 16);          \
    o.w = (unsigned)f2bf(vb.z) | ((unsigned)f2bf(vb.w) << 16);          \
    *(uint4*)&Wlds[g][kh2][ks][lane][0] = o;                            \
  }

#define GRU_TAIL(hpA, b_ih_, b_hh_, hbf_dst_, hrm_dst_)                 \
  if (kh == 1) {                                                        \
    _Pragma("unroll")                                                   \
    for (int s = 0; s < 6; ++s) *(f32x4*)&redp[mf][s][lane][0] = acc[s];\
  }                                                                     \
  __syncthreads();                                                      \
  if (kh == 0) {                                                        \
    int j = sl * 16 + lr;                                               \
    _Pragma("unroll")                                                   \
    for (int s = 0; s < 6; ++s) acc[s] += *(const f32x4*)&redp[mf][s][lane][0]; \
    float bir = (b_ih_)[j], biz = (b_ih_)[512 + j], bin_ = (b_ih_)[1024 + j]; \
    float bhr = (b_hh_)[j], bhz = (b_hh_)[512 + j], bhn = (b_hh_)[1024 + j]; \
    _Pragma("unroll")                                                   \
    for (int ri = 0; ri < 4; ++ri) {                                    \
      float ir = acc[0][ri] + bir, iz = acc[1][ri] + biz, inn = acc[2][ri] + bin_; \
      float hr2 = acc[3][ri] + bhr, hz = acc[4][ri] + bhz, hn = acc[5][ri] + bhn; \
      float rrg = 1.f / (1.f + expf(-(ir + hr2)));                      \
      float zz = 1.f / (1.f + expf(-(iz + hz)));                        \
      float nn = tanhf(inn + rrg * hn);                                 \
      float h2 = (1.f - zz) * nn + zz * (hpA)[ri];                      \
      (hpA)[ri] = h2;                                                   \
      stile[mf * 16 + gg * 4 + ri][lr] = f2bf(h2);                      \
    }                                                                   \
  }                                                                     \
  __syncthreads();                                                      \
  if (t < 64) {                                                         \
    stg_sc((hbf_dst_) + sl * 4096 + r0 * 16 + t * 8, ((const u32x4*)stile)[t]); \
    int row2 = t >> 1, c2 = t & 1;                                      \
    *(uint4*)((hrm_dst_) + (size_t)(r0 + row2) * HD + sl * 16 + c2 * 8) = \
        *(const uint4*)&stile[row2][c2 * 8];                            \
  }

__global__ __launch_bounds__(256) void enc_k(EncArgs a) {
  __shared__ ushort Wlds[6][2][8][64][8];   // 96 KB (shared by both contexts)
  __shared__ float red[2][6][64][4];
  __shared__ ushort stile[32][16];
  float (*redp)[6][64][4] = red;
  int bid = blockIdx.x;
  int rp = bid & 3, sl = bid >> 2;
  int t = threadIdx.x, lane = t & 63, w = t >> 6;
  BAR_DEFS(a.fLLC);

  LOAD_GRU_W32(a.enc_w_ih, a.enc_w_hh);
  __syncthreads();

  int mf = w & 1, kh = w >> 1;
  int lr = lane & 15, gg = lane >> 4;
  float hp[2][4] = {};

  for (int l = 0; l < SL; ++l) {
#pragma unroll
    for (int c = 0; c < 2; ++c) {
      int rg = rp + c * 4, r0 = rg * 32;
      int row_a = r0 + mf * 16 + lr;
      // gi from embedding (barrier-independent)
      const ushort* xr = a.enc_emb_bf + (size_t)l * BH + (size_t)row_a * HD +
                         kh * 256 + gg * 8;
      b16x8 xa[8];
#pragma unroll
      for (int ks = 0; ks < 8; ++ks) xa[ks] = *(const b16x8*)(xr + ks * 32);
      f32x4 acc[6] = {};
#pragma unroll
      for (int ks = 0; ks < 8; ++ks)
#pragma unroll
        for (int g3 = 0; g3 < 3; ++g3)
          acc[g3] = __builtin_amdgcn_mfma_f32_16x16x32_bf16(
              xa[ks], *(const b16x8*)(&Wlds[g3][kh][ks][lane][0]), acc[g3], 0, 0, 0);
      if (l) await(rg, (unsigned)l);
      b16x8 ha[8];
      if (l) {
        const ushort* hr = sfrag(a.enc_outs_s + (size_t)(l - 1) * BH, kh, gg, row_a);
#pragma unroll
        for (int ks = 0; ks < 8; ++ks) ha[ks] = *(const b16x8*)(hr + ks * 8192);
      } else {
#pragma unroll
        for (int ks = 0; ks < 8; ++ks) ha[ks] = b16x8{};
      }
#pragma unroll
      for (int ks = 0; ks < 8; ++ks)
#pragma unroll
        for (int g3 = 0; g3 < 3; ++g3)
          acc[3 + g3] = __builtin_amdgcn_mfma_f32_16x16x32_bf16(
              ha[ks], *(const b16x8*)(&Wlds[3 + g3][kh][ks][lane][0]),
              acc[3 + g3], 0, 0, 0);
      GRU_TAIL(hp[c], a.enc_b_ih, a.enc_b_hh, a.enc_outs_s + (size_t)l * BH,
               a.enc_outs_rm + (size_t)l * BH);
      if (l != SL - 1) produce(rg, (unsigned)(l + 1));
    }
  }
  if (kh == 0) {
#pragma unroll
    for (int c = 0; c < 2; ++c) {
      int r0 = (rp + c * 4) * 32;
      int j = sl * 16 + lr;
#pragma unroll
      for (int ri = 0; ri < 4; ++ri)
        a.Hc[(size_t)(r0 + mf * 16 + gg * 4 + ri) * HD + j] = hp[c][ri];
    }
  }
}

__global__ __launch_bounds__(256) void dec_k(DecArgs a) {
  __shared__ ushort Wlds[6][2][8][64][8];
  __shared__ DScr scr;
  __shared__ ushort stile[32][16];
  float (*redp)[6][64][4] = scr.red;
  int bid = blockIdx.x;
  int rp = bid & 3, sl = bid >> 2;
  int t = threadIdx.x, lane = t & 63, w = t >> 6;
  BAR_DEFS(a.fLLC);

  LOAD_GRU_W32(a.dec_w_ih, a.dec_w_hh);

  int mf = w & 1, kh = w >> 1;
  int lr = lane & 15, gg = lane >> 4;
  int rr = t >> 3, dp = t & 7;

  float hp[2][4] = {};
  if (kh == 0) {
#pragma unroll
    for (int c = 0; c < 2; ++c) {
      int r0 = (rp + c * 4) * 32;
      int j = sl * 16 + lr;
#pragma unroll
      for (int ri = 0; ri < 4; ++ri)
        hp[c][ri] = a.Hc[(size_t)(r0 + mf * 16 + gg * 4 + ri) * HD + j];
    }
  }
  __syncthreads();

  for (int l = 0; l < SL; ++l) {
    const ushort* h_bf = l ? a.H2_s + (size_t)(l - 1) * BH
                           : a.enc_outs_s + (size_t)31 * BH;
    // ---- attnx, both contexts ----
#pragma unroll
    for (int c = 0; c < 2; ++c) {
      int rg = rp + c * 4, r0 = rg * 32;
      int row_a = r0 + mf * 16 + lr;
      unsigned ev[32];
      const ushort* ep = a.encW + (((size_t)sl * 256 + r0 + rr) * 32) * 16 + dp * 2;
#pragma unroll
      for (int ll = 0; ll < 32; ++ll) ev[ll] = *(const unsigned*)(ep + ll * 16);
      if (l) await(rg, 2u * l);
      {
        const ushort* hr = sfrag(h_bf, kh, gg, row_a);
        const ushort* w0p = a.attn_w_bf + (size_t)lr * 1024 + 512 + kh * 256 + gg * 8;
        const ushort* w1p = a.attn_w_bf + (size_t)(16 + lr) * 1024 + 512 + kh * 256 + gg * 8;
        f32x4 a0 = {}, a1 = {};
#pragma unroll
        for (int ks = 0; ks < 8; ++ks) {
          b16x8 ah = *(const b16x8*)(hr + ks * 8192);
          a0 = __builtin_amdgcn_mfma_f32_16x16x32_bf16(
              ah, *(const b16x8*)(w0p + ks * 32), a0, 0, 0, 0);
          a1 = __builtin_amdgcn_mfma_f32_16x16x32_bf16(
              ah, *(const b16x8*)(w1p + ks * 32), a1, 0, 0, 0);
        }
#pragma unroll
        for (int ri = 0; ri < 4; ++ri) {
          scr.at.sS[kh][mf * 16 + gg * 4 + ri][lr] = a0[ri];
          scr.at.sS[kh][mf * 16 + gg * 4 + ri][16 + lr] = a1[ri];
        }
      }
      __syncthreads();
      {
        float4 pre = *(const float4*)(a.attn_pre + ((size_t)l * BA + r0 + rr) * 32 + dp * 4);
        float v0 = scr.at.sS[0][rr][dp * 4 + 0] + scr.at.sS[1][rr][dp * 4 + 0] + pre.x;
        float v1 = scr.at.sS[0][rr][dp * 4 + 1] + scr.at.sS[1][rr][dp * 4 + 1] + pre.y;
        float v2 = scr.at.sS[0][rr][dp * 4 + 2] + scr.at.sS[1][rr][dp * 4 + 2] + pre.z;
        float v3 = scr.at.sS[0][rr][dp * 4 + 3] + scr.at.sS[1][rr][dp * 4 + 3] + pre.w;
        float mx = fmaxf(fmaxf(v0, v1), fmaxf(v2, v3));
        for (int o = 1; o < 8; o <<= 1) mx = fmaxf(mx, __shfl_xor(mx, o, 64));
        float e0 = expf(v0 - mx), e1 = expf(v1 - mx);
        float e2 = expf(v2 - mx), e3 = expf(v3 - mx);
        float s = e0 + e1 + e2 + e3;
        for (int o = 1; o < 8; o <<= 1) s += __shfl_xor(s, o, 64);
        float inv = 1.f / s;
        scr.at.sAW[rr][dp * 4 + 0] = e0 * inv; scr.at.sAW[rr][dp * 4 + 1] = e1 * inv;
        scr.at.sAW[rr][dp * 4 + 2] = e2 * inv; scr.at.sAW[rr][dp * 4 + 3] = e3 * inv;
      }
      __syncthreads();
      {
        const float* cp = a.comb_pre + ((size_t)l * BA + r0 + rr) * HD + sl * 16 + dp * 2;
        float f0 = cp[0], f1 = cp[1];
#pragma unroll
        for (int ll = 0; ll < 32; ++ll) {
          float aw = scr.at.sAW[rr][ll];
          f0 += aw * __uint_as_float(ev[ll] << 16);
          f1 += aw * __uint_as_float(ev[ll] & 0xffff0000u);
        }
        f0 = fmaxf(f0, 0.f); f1 = fmaxf(f1, 0.f);
        *(unsigned*)&stile[rr][dp * 2] =
            (unsigned)f2bf(f0) | ((unsigned)f2bf(f1) << 16);
      }
      __syncthreads();
      if (t < 64)
        stg_sc(a.x_s + (size_t)l * BH + sl * 4096 + r0 * 16 + t * 8,
               ((const u32x4*)stile)[t]);
      produce(rg, 2u * l + 1);
    }
    // ---- gru, both contexts ----
#pragma unroll
    for (int c = 0; c < 2; ++c) {
      int rg = rp + c * 4, r0 = rg * 32;
      int row_a = r0 + mf * 16 + lr;
      f32x4 acc[6] = {};
      {
        const ushort* hr = sfrag(h_bf, kh, gg, row_a);
        b16x8 ha[8];
#pragma unroll
        for (int ks = 0; ks < 8; ++ks) ha[ks] = *(const b16x8*)(hr + ks * 8192);
#pragma unroll
        for (int ks = 0; ks < 8; ++ks)
#pragma unroll
          for (int g3 = 0; g3 < 3; ++g3)
            acc[3 + g3] = __builtin_amdgcn_mfma_f32_16x16x32_bf16(
                ha[ks], *(const b16x8*)(&Wlds[3 + g3][kh][ks][lane][0]),
                acc[3 + g3], 0, 0, 0);
      }
      await(rg, 2u * l + 1);
      {
        const ushort* xr = sfrag(a.x_s + (size_t)l * BH, kh, gg, row_a);
        b16x8 xa[8];
#pragma unroll
        for (int ks = 0; ks < 8; ++ks) xa[ks] = *(const b16x8*)(xr + ks * 8192);
#pragma unroll
        for (int ks = 0; ks < 8; ++ks)
#pragma unroll
          for (int g3 = 0; g3 < 3; ++g3)
            acc[g3] = __builtin_amdgcn_mfma_f32_16x16x32_bf16(
                xa[ks], *(const b16x8*)(&Wlds[g3][kh][ks][lane][0]),
                acc[g3], 0, 0, 0);
      }
      GRU_TAIL(hp[c], a.dec_b_ih, a.dec_b_hh, a.H2_s + (size_t)l * BH,
               a.H2_rm + (size_t)l * BH);
      if (l != SL - 1) produce(rg, 2u * l + 2);
    }
  }
}

// ---------------- one-pass register-resident log-softmax ----------------
__global__ __launch_bounds__(256) void lsesub_k(float* __restrict__ logits) {
  __shared__ float redm[4], reds[4];
  int row = blockIdx.x, t = threadIdx.x;
  float4* p = (float4*)(logits + (size_t)row * VOC);
  float4 v[10];
  float m = -1e30f, s = 0.f;
#pragma unroll
  for (int j = 0; j < 10; ++j) {
    int i = t + j * 256;
    if (i < 2500) {
      v[j] = p[i];
      float mx = fmaxf(fmaxf(v[j].x, v[j].y), fmaxf(v[j].z, v[j].w));
      if (mx > m) { s *= expf(m - mx); m = mx; }
      s += expf(v[j].x - m) + expf(v[j].y - m) + expf(v[j].z - m) + expf(v[j].w - m);
    }
  }
#pragma unroll
  for (int o = 32; o; o >>= 1) {
    float m2 = __shfl_xor(m, o, 64), s2 = __shfl_xor(s, o, 64);
    float mn = fmaxf(m, m2);
    s = s * expf(m - mn) + s2 * expf(m2 - mn);
    m = mn;
  }
  if ((t & 63) == 0) { redm[t >> 6] = m; reds[t >> 6] = s; }
  __syncthreads();
  float mf = fmaxf(fmaxf(redm[0], redm[1]), fmaxf(redm[2], redm[3]));
  float sf = reds[0] * expf(redm[0] - mf) + reds[1] * expf(redm[1] - mf) +
             reds[2] * expf(redm[2] - mf) + reds[3] * expf(redm[3] - mf);
  float z = mf + logf(sf);
#pragma unroll
  for (int j = 0; j < 10; ++j) {
    int i = t + j * 256;
    if (i < 2500) {
      v[j].x -= z; v[j].y -= z; v[j].z -= z; v[j].w -= z;
      p[i] = v[j];
    }
  }
}

extern "C" void kernel_launch(void* const* d_in, const int* in_sizes, int n_in,
                              void* d_out, int out_size, void* d_ws, size_t ws_size,
                              hipStream_t stream) {
  (void)in_sizes; (void)n_in; (void)out_size; (void)ws_size;
  const int* in_tok = (const int*)d_in[0];
  const int* tgt_tok = (const int*)d_in[1];
  const float* enc_embed = (const float*)d_in[2];
  const float* enc_w_ih = (const float*)d_in[3];
  const float* enc_w_hh = (const float*)d_in[4];
  const float* enc_b_ih = (const float*)d_in[5];
  const float* enc_b_hh = (const float*)d_in[6];
  const float* dec_embed = (const float*)d_in[7];
  const float* attn_w = (const float*)d_in[8];
  const float* attn_b = (const float*)d_in[9];
  const float* comb_w = (const float*)d_in[10];
  const float* comb_b = (const float*)d_in[11];
  const float* dec_w_ih = (const float*)d_in[12];
  const float* dec_w_hh = (const float*)d_in[13];
  const float* dec_b_ih = (const float*)d_in[14];
  const float* dec_b_hh = (const float*)d_in[15];
  const float* out_w = (const float*)d_in[16];
  const float* out_b = (const float*)d_in[17];
  float* out = (float*)d_out;

  char* ws = (char*)d_ws;
  size_t off = 0;
  auto carve = [&](size_t bytes) {
    void* p = ws + off;
    off += (bytes + 255) & ~(size_t)255;
    return p;
  };
  ushort* comb_w_bf  = (ushort*)carve(512 * 1024 * 2);
  ushort* attn_w_bf  = (ushort*)carve(32 * 1024 * 2);
  ushort* out_w_bf   = (ushort*)carve((size_t)VOC * HD * 2);
  ushort* enc_emb_bf = (ushort*)carve((size_t)SL * BA * HD * 2);
  ushort* dec_emb_bf = (ushort*)carve((size_t)SL * BA * HD * 2);
  float* attn_pre    = (float*)carve((size_t)SL * BA * 32 * 4);
  float* comb_pre    = (float*)carve((size_t)SL * BA * HD * 4);
  ushort* enc_outs_s = (ushort*)carve((size_t)SL * BA * HD * 2);
  ushort* enc_outs_rm= (ushort*)carve((size_t)SL * BA * HD * 2);
  ushort* encW       = (ushort*)carve((size_t)SL * BA * HD * 2);
  ushort* H2_s       = (ushort*)carve((size_t)SL * BA * HD * 2);
  ushort* H2_rm      = (ushort*)carve((size_t)SL * BA * HD * 2);
  ushort* x_s        = (ushort*)carve((size_t)SL * BA * HD * 2);
  float* Hc          = (float*)carve((size_t)BA * HD * 4);
  unsigned* fE_LLC   = (unsigned*)carve(8 * 32 * 16 * 4);
  unsigned* fD_LLC   = (unsigned*)carve(8 * 32 * 16 * 4);

  // ---- setup ----
  hipMemsetAsync(fE_LLC, 0, 8 * 32 * 16 * 4, stream);
  hipMemsetAsync(fD_LLC, 0, 8 * 32 * 16 * 4, stream);
  cvt3_k<<<5544, 256, 0, stream>>>(out_w, out_w_bf, comb_w, comb_w_bf,
                                   attn_w, attn_w_bf);
  gather2_k<<<2 * SL * BA, 64, 0, stream>>>(enc_embed, dec_embed, in_tok,
                                            tgt_tok, enc_emb_bf, dec_emb_bf);

  // ---- merged decoder precomputes (attn_pre + comb_pre) ----
  gemm2_k<<<dim3(128, 9), 256, 0, stream>>>(dec_emb_bf, comb_w_bf, attn_w_bf,
                                            comb_b, attn_b, comb_pre, attn_pre);

  // ---- encoder (persistent, cooperative, 128 blocks x 2 contexts) ----
  EncArgs ea;
  ea.enc_emb_bf = enc_emb_bf;
  ea.enc_w_ih = enc_w_ih; ea.enc_w_hh = enc_w_hh;
  ea.enc_b_ih = enc_b_ih; ea.enc_b_hh = enc_b_hh;
  ea.enc_outs_s = enc_outs_s;
  ea.enc_outs_rm = enc_outs_rm;
  ea.Hc = Hc;
  ea.fLLC = fE_LLC;
  void* ekargs[] = { (void*)&ea };
  hipError_t ce = hipLaunchCooperativeKernel(enc_k, dim3(128), dim3(256),
                                             ekargs, 0, stream);
  if (ce != hipSuccess) enc_k<<<128, 256, 0, stream>>>(ea);

  // ---- encW = enc_outs @ comb_w[:,512:].T (interleaved bf16) ----
  gemmW_k<<<dim3(128, 8), 256, 0, stream>>>(enc_outs_rm, comb_w_bf, encW);

  // ---- decoder (persistent, cooperative, 128 blocks x 2 contexts) ----
  DecArgs da;
  da.dec_w_ih = dec_w_ih; da.dec_w_hh = dec_w_hh;
  da.dec_b_ih = dec_b_ih; da.dec_b_hh = dec_b_hh;
  da.attn_w_bf = attn_w_bf;
  da.attn_pre = attn_pre;
  da.comb_pre = comb_pre;
  da.enc_outs_s = enc_outs_s;
  da.encW = encW;
  da.Hc = Hc;
  da.H2_s = H2_s; da.H2_rm = H2_rm; da.x_s = x_s;
  da.fLLC = fD_LLC;
  void* dkargs[] = { (void*)&da };
  ce = hipLaunchCooperativeKernel(dec_k, dim3(128), dim3(256),
                                  dkargs, 0, stream);
  if (ce != hipSuccess) dec_k<<<128, 256, 0, stream>>>(da);

  // ---- output projection (128x128 tile) + one-pass log_softmax ----
  gemmbig_k<<<dim3(64, 79), 256, 0, stream>>>(H2_rm, out_w_bf, VOC,
                                              out_b, out, VOC);
  lsesub_k<<<SL * BA, 256, 0, stream>>>(out);
}

// Round 12
// 810.571 us; speedup vs baseline: 1.4593x; 1.4593x over previous
//
#include <hip/hip_runtime.h>

#define HD 512
#define VOC 10000
#define SL 32
#define BA 256
#define BH (BA*HD)

typedef __bf16 b16x8 __attribute__((ext_vector_type(8)));
typedef float f32x4 __attribute__((ext_vector_type(4)));
typedef unsigned u32x4 __attribute__((ext_vector_type(4)));

__device__ __forceinline__ ushort f2bf(float x) {
  unsigned u = __float_as_uint(x);
  u += 0x7fffu + ((u >> 16) & 1u);
  return (ushort)(u >> 16);
}

// ---- LLC write-through (sc0 sc1), plain L2, sc0 (L1-bypass) accessors ----
__device__ __forceinline__ void stg_sc(void* p, u32x4 v) {
  asm volatile("global_store_dwordx4 %0, %1, off sc0 sc1"
               :: "v"(p), "v"(v) : "memory");
}
__device__ __forceinline__ void stg_sc1(void* p, unsigned v) {
  asm volatile("global_store_dword %0, %1, off sc0 sc1"
               :: "v"(p), "v"(v) : "memory");
}
__device__ __forceinline__ void stg_plain(void* p, unsigned v) {
  asm volatile("global_store_dword %0, %1, off"
               :: "v"(p), "v"(v) : "memory");
}
__device__ __forceinline__ unsigned ldg_sc0(const void* p) {
  unsigned v;
  asm volatile("global_load_dword %0, %1, off sc0"
               : "=v"(v) : "v"(p) : "memory");
  asm volatile("s_waitcnt vmcnt(0)" ::: "memory");
  return v;
}
__device__ __forceinline__ unsigned ldg_sc1(const void* p) {
  unsigned v;
  asm volatile("global_load_dword %0, %1, off sc0 sc1"
               : "=v"(v) : "v"(p) : "memory");
  asm volatile("s_waitcnt vmcnt(0)" ::: "memory");
  return v;
}
__device__ __forceinline__ void vmwait0() {
  asm volatile("s_waitcnt vmcnt(0)" ::: "memory");
  __builtin_amdgcn_sched_barrier(0);
}

// ---------------- merged fp32 -> bf16 converts (out_w | comb_w | attn_w) ----------------
__global__ __launch_bounds__(256) void cvt3_k(
    const float* __restrict__ w_out, ushort* __restrict__ o_out,
    const float* __restrict__ w_comb, ushort* __restrict__ o_comb,
    const float* __restrict__ w_attn, ushort* __restrict__ o_attn) {
  int b = blockIdx.x;
  const float* in; ushort* out; int i; int n4;
  if (b < 5000)      { in = w_out;  out = o_out;  i = b * 256 + threadIdx.x;          n4 = 1280000; }
  else if (b < 5512) { in = w_comb; out = o_comb; i = (b - 5000) * 256 + threadIdx.x; n4 = 131072; }
  else               { in = w_attn; out = o_attn; i = (b - 5512) * 256 + threadIdx.x; n4 = 8192; }
  if (i < n4) {
    float4 v = ((const float4*)in)[i];
    ((ushort4*)out)[i] = make_ushort4(f2bf(v.x), f2bf(v.y), f2bf(v.z), f2bf(v.w));
  }
}

// ---------------- merged embedding gathers ----------------
__global__ __launch_bounds__(64) void gather2_k(
    const float* __restrict__ enc_t, const float* __restrict__ dec_t,
    const int* __restrict__ in_tok, const int* __restrict__ tgt_tok,
    ushort* __restrict__ enc_o, ushort* __restrict__ dec_o) {
  int bid = blockIdx.x;
  int isDec = bid >= SL * BA;
  int row = isDec ? bid - SL * BA : bid;
  int l = row >> 8, b = row & 255;
  int tok = isDec ? ((l == 0) ? 1 : tgt_tok[b * SL + l - 1]) : in_tok[b * SL + l];
  const float* table = isDec ? dec_t : enc_t;
  ushort* out = isDec ? dec_o : enc_o;
  const float4* src = (const float4*)(table + (size_t)tok * HD);
  int t = threadIdx.x;
  float4 v0 = src[t * 2], v1 = src[t * 2 + 1];
  uint4 o;
  o.x = (unsigned)f2bf(v0.x) | ((unsigned)f2bf(v0.y) << 16);
  o.y = (unsigned)f2bf(v0.z) | ((unsigned)f2bf(v0.w) << 16);
  o.z = (unsigned)f2bf(v1.x) | ((unsigned)f2bf(v1.y) << 16);
  o.w = (unsigned)f2bf(v1.z) | ((unsigned)f2bf(v1.w) << 16);
  *(uint4*)(out + (size_t)row * HD + t * 8) = o;
}

// ---------------- merged precompute GEMM: attn_pre + comb_pre ----------------
__global__ __launch_bounds__(256) void gemm2_k(
    const ushort* __restrict__ A,
    const ushort* __restrict__ Wc, const ushort* __restrict__ Wa,
    const float* __restrict__ bc, const float* __restrict__ ba,
    float* __restrict__ outc, float* __restrict__ outa) {
  __shared__ ushort lsA[4][64][8];
  __shared__ ushort lsB[4][64][8];
  __shared__ float ctile[64][68];
  int t = threadIdx.x;
  int lane = t & 63, w = t >> 6;
  int by = blockIdx.y;
  const ushort* W; const float* bias; float* outf; int N, n0, ldc;
  if (by < 8) { W = Wc; bias = bc; outf = outc; N = 512; n0 = by * 64; ldc = 512; }
  else        { W = Wa; bias = ba; outf = outa; N = 32;  n0 = 0;       ldc = 32; }
  int m0 = blockIdx.x * 64;
  f32x4 acc[4] = {};
  int sr = t >> 2, g = t & 3;
  const ushort* Ap = A + (size_t)(m0 + sr) * HD + g * 8;
  int nr = n0 + sr; if (nr > N - 1) nr = N - 1;
  const ushort* Wp = W + (size_t)nr * 1024 + g * 8;
  for (int ks = 0; ks < 16; ++ks) {
    *(uint4*)(&lsA[g][sr][0]) = *(const uint4*)(Ap + ks * 32);
    *(uint4*)(&lsB[g][sr][0]) = *(const uint4*)(Wp + ks * 32);
    __syncthreads();
    int gg = lane >> 4, r = lane & 15;
    b16x8 bf = *(const b16x8*)(&lsB[gg][w * 16 + r][0]);
#pragma unroll
    for (int mi = 0; mi < 4; ++mi) {
      b16x8 af = *(const b16x8*)(&lsA[gg][mi * 16 + r][0]);
      acc[mi] = __builtin_amdgcn_mfma_f32_16x16x32_bf16(af, bf, acc[mi], 0, 0, 0);
    }
    __syncthreads();
  }
  int gg = lane >> 4, cl = lane & 15;
  int tcol = w * 16 + cl;
  int bc2 = n0 + tcol; if (bc2 > N - 1) bc2 = N - 1;
  float bv = bias[bc2];
#pragma unroll
  for (int mi = 0; mi < 4; ++mi)
#pragma unroll
    for (int r = 0; r < 4; ++r)
      ctile[mi * 16 + gg * 4 + r][tcol] = acc[mi][r] + bv;
  __syncthreads();
  int row = t >> 2, q = t & 3;
#pragma unroll
  for (int j = 0; j < 4; ++j) {
    int c = q * 16 + j * 4;
    if (n0 + c + 3 <= N - 1)
      *(float4*)(outf + (size_t)(m0 + row) * ldc + n0 + c) =
          *(const float4*)&ctile[row][c];
  }
}

// ---------------- encW GEMM -> interleaved layout [sl][b][ll][16] ----------------
__global__ __launch_bounds__(256) void gemmW_k(
    const ushort* __restrict__ A, const ushort* __restrict__ W,
    ushort* __restrict__ outI) {
  __shared__ ushort lsA[4][64][8];
  __shared__ ushort lsB[4][64][8];
  __shared__ ushort ctileS[64][64];
  int t = threadIdx.x, lane = t & 63, w = t >> 6;
  int m0 = blockIdx.x * 64, n0 = blockIdx.y * 64;
  f32x4 acc[4] = {};
  int sr = t >> 2, g = t & 3;
  const ushort* Ap = A + (size_t)(m0 + sr) * HD + g * 8;
  const ushort* Wp = W + (size_t)(n0 + sr) * 1024 + 512 + g * 8;
  for (int ks = 0; ks < 16; ++ks) {
    *(uint4*)(&lsA[g][sr][0]) = *(const uint4*)(Ap + ks * 32);
    *(uint4*)(&lsB[g][sr][0]) = *(const uint4*)(Wp + ks * 32);
    __syncthreads();
    int gg = lane >> 4, r = lane & 15;
    b16x8 bf = *(const b16x8*)(&lsB[gg][w * 16 + r][0]);
#pragma unroll
    for (int mi = 0; mi < 4; ++mi) {
      b16x8 af = *(const b16x8*)(&lsA[gg][mi * 16 + r][0]);
      acc[mi] = __builtin_amdgcn_mfma_f32_16x16x32_bf16(af, bf, acc[mi], 0, 0, 0);
    }
    __syncthreads();
  }
  int gg = lane >> 4, cl = lane & 15;
  int tcol = w * 16 + cl;
#pragma unroll
  for (int mi = 0; mi < 4; ++mi)
#pragma unroll
    for (int r = 0; r < 4; ++r)
      ctileS[mi * 16 + gg * 4 + r][tcol] = f2bf(acc[mi][r]);
  __syncthreads();
  int l = m0 >> 8, b0 = m0 & 255;
  int sl_i = t >> 6, tid = t & 63;
  int sl_g = (n0 >> 4) + sl_i;
  ushort* dst = outI + ((((size_t)sl_g * 256 + b0 + tid) * 32) + l) * 16;
  *(uint4*)dst = *(const uint4*)&ctileS[tid][sl_i * 16];
  *(uint4*)(dst + 8) = *(const uint4*)&ctileS[tid][sl_i * 16 + 8];
}

// ---------------- bf16 GEMM 128x128 tile (big output projection; verified r11) ----------------
__global__ __launch_bounds__(256) void gemmbig_k(
    const ushort* __restrict__ A, const ushort* __restrict__ W,
    int N, const float* __restrict__ bias,
    float* __restrict__ outf, int ldc) {
  __shared__ ushort lsA[4][128][8];
  __shared__ ushort lsB[4][128][8];
  __shared__ float ctile[64][132];
  int t = threadIdx.x, lane = t & 63, w = t >> 6;
  int m0 = blockIdx.x * 128, n0 = blockIdx.y * 128;
  f32x4 acc[8][2] = {};
  int arow = t >> 1, ag = t & 1;
  const ushort* Ap = A + (size_t)(m0 + arow) * HD + ag * 16;
  int nr = n0 + arow; if (nr > N - 1) nr = N - 1;
  const ushort* Wp = W + (size_t)nr * HD + ag * 16;
  for (int ks = 0; ks < 16; ++ks) {
    *(uint4*)(&lsA[ag * 2][arow][0])     = *(const uint4*)(Ap + ks * 32);
    *(uint4*)(&lsA[ag * 2 + 1][arow][0]) = *(const uint4*)(Ap + ks * 32 + 8);
    *(uint4*)(&lsB[ag * 2][arow][0])     = *(const uint4*)(Wp + ks * 32);
    *(uint4*)(&lsB[ag * 2 + 1][arow][0]) = *(const uint4*)(Wp + ks * 32 + 8);
    __syncthreads();
    int gg = lane >> 4, r = lane & 15;
    b16x8 bf0 = *(const b16x8*)(&lsB[gg][w * 32 + r][0]);
    b16x8 bf1 = *(const b16x8*)(&lsB[gg][w * 32 + 16 + r][0]);
#pragma unroll
    for (int mi = 0; mi < 8; ++mi) {
      b16x8 af = *(const b16x8*)(&lsA[gg][mi * 16 + r][0]);
      acc[mi][0] = __builtin_amdgcn_mfma_f32_16x16x32_bf16(af, bf0, acc[mi][0], 0, 0, 0);
      acc[mi][1] = __builtin_amdgcn_mfma_f32_16x16x32_bf16(af, bf1, acc[mi][1], 0, 0, 0);
    }
    __syncthreads();
  }
  int gg = lane >> 4, cl = lane & 15;
#pragma unroll
  for (int half = 0; half < 2; ++half) {
    __syncthreads();
#pragma unroll
    for (int mi = 0; mi < 4; ++mi) {
      int m = half * 4 + mi;
#pragma unroll
      for (int nf = 0; nf < 2; ++nf) {
        int tc = w * 32 + nf * 16 + cl;
        int bc = n0 + tc; if (bc > N - 1) bc = N - 1;
        float bv = bias[bc];
#pragma unroll
        for (int r2 = 0; r2 < 4; ++r2)
          ctile[mi * 16 + gg * 4 + r2][tc] = acc[m][nf][r2] + bv;
      }
    }
    __syncthreads();
    int row = t >> 2, q = t & 3;
#pragma unroll
    for (int j = 0; j < 8; ++j) {
      int c = q * 32 + j * 4;
      if (n0 + c + 3 <= N - 1)
        *(float4*)(outf + (size_t)(m0 + half * 64 + row) * ldc + n0 + c) =
            *(const float4*)&ctile[row][c];
    }
  }
}

// ================= persistent recurrence (round-10 structure) =================
// 256 blocks, rg = bid&7, sl = bid>>3. Sliced activations [l][sl][256][16],
// encW interleaved [sl][b][ll][16]. Hybrid L2/LLC barrier, produce/await split.

__device__ __forceinline__ const ushort* sfrag(const ushort* base, int kh,
                                               int gg, int row) {
  return base + (kh * 16 + (gg >> 1)) * 4096 + row * 16 + (gg & 1) * 8;
}

struct EncArgs {
  const ushort* enc_emb_bf;
  const float* enc_w_ih; const float* enc_w_hh;
  const float* enc_b_ih; const float* enc_b_hh;
  ushort* enc_outs_s;
  ushort* enc_outs_rm;
  float* Hc;
  unsigned* fL2; unsigned* fLLC;
};

struct DecArgs {
  const float* dec_w_ih; const float* dec_w_hh;
  const float* dec_b_ih; const float* dec_b_hh;
  const ushort* attn_w_bf;
  const float* attn_pre;
  const float* comb_pre;
  const ushort* enc_outs_s;
  const ushort* encW;
  const float* Hc;
  ushort* H2_s; ushort* H2_rm; ushort* x_s;
  unsigned* fL2; unsigned* fLLC;
};

union DScr {
  float red[2][6][64][4];
  struct { float sS[2][32][33]; float sAW[32][33]; } at;
};

#define BAR_DEFS(fL2p, fLLCp)                                           \
  auto produce = [&](unsigned val) {                                    \
    __syncthreads();                                                    \
    if (w == 0) {                                                       \
      vmwait0();                                                        \
      if (lane == 0) {                                                  \
        stg_plain(&(fL2p)[sl * 4], val);                                \
        stg_sc1(&(fLLCp)[sl * 16], val);                                \
      }                                                                 \
    }                                                                   \
  };                                                                    \
  auto await = [&](unsigned val) {                                      \
    if (w == 0) {                                                       \
      int it = 0;                                                       \
      for (;;) {                                                        \
        unsigned v = ldg_sc0(&(fL2p)[(lane & 31) * 4]);                 \
        if (!__any(v < val)) break;                                     \
        if ((++it & 3) == 0) {                                          \
          unsigned v2 = ldg_sc1(&(fLLCp)[(lane & 31) * 16]);            \
          if (!__any(v < val && v2 < val)) break;                       \
        }                                                               \
        __builtin_amdgcn_s_sleep(1);                                    \
      }                                                                 \
    }                                                                   \
    __syncthreads();                                                    \
  }

#define LOAD_GRU_W32(Wih, Whh)                                          \
  for (int c = w; c < 96; c += 4) {                                     \
    int g = c >> 4, rem = c & 15, kh2 = rem >> 3, ks = rem & 7;         \
    const float* src = (g < 3) ? (Wih) : (Whh);                         \
    int gr = (g % 3) * 512 + sl * 16 + (lane & 15);                     \
    int col = kh2 * 256 + ks * 32 + (lane >> 4) * 8;                    \
    const float4* s4 = (const float4*)(src + (size_t)gr * HD + col);    \
    float4 va = s4[0], vb = s4[1];                                      \
    uint4 o;                                                            \
    o.x = (unsigned)f2bf(va.x) | ((unsigned)f2bf(va.y) << 16);          \
    o.y = (unsigned)f2bf(va.z) | ((unsigned)f2bf(va.w) << 16);          \
    o.z = (unsigned)f2bf(vb.x) | ((unsigned)f2bf(vb.y) << 16);          \
    o.w = (unsigned)f2bf(vb.z) | ((unsigned)f2bf(vb.w) << 16);          \
    *(uint4*)&Wlds[g][kh2][ks][lane][0] = o;                            \
  }

#define GRU_TAIL(b_ih_, b_hh_, hbf_dst_, hrm_dst_)                      \
  if (kh == 1) {                                                        \
    _Pragma("unroll")                                                   \
    for (int s = 0; s < 6; ++s) *(f32x4*)&redp[mf][s][lane][0] = acc[s];\
  }                                                                     \
  __syncthreads();                                                      \
  if (kh == 0) {                                                        \
    int j = sl * 16 + lr;                                               \
    _Pragma("unroll")                                                   \
    for (int s = 0; s < 6; ++s) acc[s] += *(const f32x4*)&redp[mf][s][lane][0]; \
    float bir = (b_ih_)[j], biz = (b_ih_)[512 + j], bin_ = (b_ih_)[1024 + j]; \
    float bhr = (b_hh_)[j], bhz = (b_hh_)[512 + j], bhn = (b_hh_)[1024 + j]; \
    _Pragma("unroll")                                                   \
    for (int ri = 0; ri < 4; ++ri) {                                    \
      float ir = acc[0][ri] + bir, iz = acc[1][ri] + biz, inn = acc[2][ri] + bin_; \
      float hr2 = acc[3][ri] + bhr, hz = acc[4][ri] + bhz, hn = acc[5][ri] + bhn; \
      float rrg = 1.f / (1.f + expf(-(ir + hr2)));                      \
      float zz = 1.f / (1.f + expf(-(iz + hz)));                        \
      float nn = tanhf(inn + rrg * hn);                                 \
      float h2 = (1.f - zz) * nn + zz * hp[ri];                         \
      hp[ri] = h2;                                                      \
      stile[mf * 16 + gg * 4 + ri][lr] = f2bf(h2);                      \
    }                                                                   \
  }                                                                     \
  __syncthreads();                                                      \
  if (t < 64) {                                                         \
    stg_sc((hbf_dst_) + sl * 4096 + r0 * 16 + t * 8, ((const u32x4*)stile)[t]); \
    int row2 = t >> 1, c2 = t & 1;                                      \
    *(uint4*)((hrm_dst_) + (size_t)(r0 + row2) * HD + sl * 16 + c2 * 8) = \
        *(const uint4*)&stile[row2][c2 * 8];                            \
  }

__global__ __launch_bounds__(256) void enc_k(EncArgs a) {
  __shared__ ushort Wlds[6][2][8][64][8];
  __shared__ float red[2][6][64][4];
  __shared__ ushort stile[32][16];
  float (*redp)[6][64][4] = red;
  int bid = blockIdx.x;
  int rg = bid & 7, sl = bid >> 3;
  int t = threadIdx.x, lane = t & 63, w = t >> 6;
  int r0 = rg * 32;
  unsigned* fL2 = a.fL2 + rg * 32 * 4;
  unsigned* fLLC = a.fLLC + rg * 32 * 16;
  BAR_DEFS(fL2, fLLC);

  LOAD_GRU_W32(a.enc_w_ih, a.enc_w_hh);
  __syncthreads();

  int mf = w & 1, kh = w >> 1;
  int lr = lane & 15, gg = lane >> 4;
  int row_a = r0 + mf * 16 + lr;
  float hp[4] = {0.f, 0.f, 0.f, 0.f};

  for (int l = 0; l < SL; ++l) {
    const ushort* xr = a.enc_emb_bf + (size_t)l * BH + (size_t)row_a * HD +
                       kh * 256 + gg * 8;
    b16x8 xa[8];
#pragma unroll
    for (int ks = 0; ks < 8; ++ks) xa[ks] = *(const b16x8*)(xr + ks * 32);
    f32x4 acc[6] = {};
#pragma unroll
    for (int ks = 0; ks < 8; ++ks)
#pragma unroll
      for (int g3 = 0; g3 < 3; ++g3)
        acc[g3] = __builtin_amdgcn_mfma_f32_16x16x32_bf16(
            xa[ks], *(const b16x8*)(&Wlds[g3][kh][ks][lane][0]), acc[g3], 0, 0, 0);
    if (l) await((unsigned)l);
    b16x8 ha[8];
    if (l) {
      const ushort* hr = sfrag(a.enc_outs_s + (size_t)(l - 1) * BH, kh, gg, row_a);
#pragma unroll
      for (int ks = 0; ks < 8; ++ks) ha[ks] = *(const b16x8*)(hr + ks * 8192);
    } else {
#pragma unroll
      for (int ks = 0; ks < 8; ++ks) ha[ks] = b16x8{};
    }
#pragma unroll
    for (int ks = 0; ks < 8; ++ks)
#pragma unroll
      for (int g3 = 0; g3 < 3; ++g3)
        acc[3 + g3] = __builtin_amdgcn_mfma_f32_16x16x32_bf16(
            ha[ks], *(const b16x8*)(&Wlds[3 + g3][kh][ks][lane][0]),
            acc[3 + g3], 0, 0, 0);
    GRU_TAIL(a.enc_b_ih, a.enc_b_hh, a.enc_outs_s + (size_t)l * BH,
             a.enc_outs_rm + (size_t)l * BH);
    if (l != SL - 1) produce((unsigned)(l + 1));
  }
  if (kh == 0) {
    int j = sl * 16 + lr;
#pragma unroll
    for (int ri = 0; ri < 4; ++ri)
      a.Hc[(size_t)(r0 + mf * 16 + gg * 4 + ri) * HD + j] = hp[ri];
  }
}

__global__ __launch_bounds__(256) void dec_k(DecArgs a) {
  __shared__ ushort Wlds[6][2][8][64][8];
  __shared__ DScr scr;
  __shared__ ushort stile[32][16];
  float (*redp)[6][64][4] = scr.red;
  int bid = blockIdx.x;
  int rg = bid & 7, sl = bid >> 3;
  int t = threadIdx.x, lane = t & 63, w = t >> 6;
  int r0 = rg * 32;
  unsigned* fL2 = a.fL2 + rg * 32 * 4;
  unsigned* fLLC = a.fLLC + rg * 32 * 16;
  BAR_DEFS(fL2, fLLC);

  LOAD_GRU_W32(a.dec_w_ih, a.dec_w_hh);

  int mf = w & 1, kh = w >> 1;
  int lr = lane & 15, gg = lane >> 4;
  int row_a = r0 + mf * 16 + lr;
  int rr = t >> 3, dp = t & 7;

  float hp[4] = {0.f, 0.f, 0.f, 0.f};
  if (kh == 0) {
    int j = sl * 16 + lr;
#pragma unroll
    for (int ri = 0; ri < 4; ++ri)
      hp[ri] = a.Hc[(size_t)(r0 + mf * 16 + gg * 4 + ri) * HD + j];
  }
  __syncthreads();

  for (int l = 0; l < SL; ++l) {
    const ushort* h_bf = l ? a.H2_s + (size_t)(l - 1) * BH
                           : a.enc_outs_s + (size_t)31 * BH;
    // ================= attnx =================
    unsigned ev[32];
    {
      const ushort* ep = a.encW + (((size_t)sl * 256 + r0 + rr) * 32) * 16 + dp * 2;
#pragma unroll
      for (int ll = 0; ll < 32; ++ll)
        ev[ll] = *(const unsigned*)(ep + ll * 16);
    }
    if (l) await(2u * l);
    {
      const ushort* hr = sfrag(h_bf, kh, gg, row_a);
      const ushort* w0 = a.attn_w_bf + (size_t)lr * 1024 + 512 + kh * 256 + gg * 8;
      const ushort* w1 = a.attn_w_bf + (size_t)(16 + lr) * 1024 + 512 + kh * 256 + gg * 8;
      f32x4 a0 = {}, a1 = {};
#pragma unroll
      for (int ks = 0; ks < 8; ++ks) {
        b16x8 ah = *(const b16x8*)(hr + ks * 8192);
        a0 = __builtin_amdgcn_mfma_f32_16x16x32_bf16(
            ah, *(const b16x8*)(w0 + ks * 32), a0, 0, 0, 0);
        a1 = __builtin_amdgcn_mfma_f32_16x16x32_bf16(
            ah, *(const b16x8*)(w1 + ks * 32), a1, 0, 0, 0);
      }
#pragma unroll
      for (int ri = 0; ri < 4; ++ri) {
        scr.at.sS[kh][mf * 16 + gg * 4 + ri][lr] = a0[ri];
        scr.at.sS[kh][mf * 16 + gg * 4 + ri][16 + lr] = a1[ri];
      }
    }
    __syncthreads();
    {
      float4 pre = *(const float4*)(a.attn_pre + ((size_t)l * BA + r0 + rr) * 32 + dp * 4);
      float v0 = scr.at.sS[0][rr][dp * 4 + 0] + scr.at.sS[1][rr][dp * 4 + 0] + pre.x;
      float v1 = scr.at.sS[0][rr][dp * 4 + 1] + scr.at.sS[1][rr][dp * 4 + 1] + pre.y;
      float v2 = scr.at.sS[0][rr][dp * 4 + 2] + scr.at.sS[1][rr][dp * 4 + 2] + pre.z;
      float v3 = scr.at.sS[0][rr][dp * 4 + 3] + scr.at.sS[1][rr][dp * 4 + 3] + pre.w;
      float mx = fmaxf(fmaxf(v0, v1), fmaxf(v2, v3));
      for (int o = 1; o < 8; o <<= 1) mx = fmaxf(mx, __shfl_xor(mx, o, 64));
      float e0 = expf(v0 - mx), e1 = expf(v1 - mx);
      float e2 = expf(v2 - mx), e3 = expf(v3 - mx);
      float s = e0 + e1 + e2 + e3;
      for (int o = 1; o < 8; o <<= 1) s += __shfl_xor(s, o, 64);
      float inv = 1.f / s;
      scr.at.sAW[rr][dp * 4 + 0] = e0 * inv; scr.at.sAW[rr][dp * 4 + 1] = e1 * inv;
      scr.at.sAW[rr][dp * 4 + 2] = e2 * inv; scr.at.sAW[rr][dp * 4 + 3] = e3 * inv;
    }
    __syncthreads();
    {
      const float* cp = a.comb_pre + ((size_t)l * BA + r0 + rr) * HD + sl * 16 + dp * 2;
      float f0 = cp[0], f1 = cp[1];
#pragma unroll
      for (int ll = 0; ll < 32; ++ll) {
        float aw = scr.at.sAW[rr][ll];
        f0 += aw * __uint_as_float(ev[ll] << 16);
        f1 += aw * __uint_as_float(ev[ll] & 0xffff0000u);
      }
      f0 = fmaxf(f0, 0.f); f1 = fmaxf(f1, 0.f);
      *(unsigned*)&stile[rr][dp * 2] =
          (unsigned)f2bf(f0) | ((unsigned)f2bf(f1) << 16);
    }
    __syncthreads();
    if (t < 64)
      stg_sc(a.x_s + (size_t)l * BH + sl * 4096 + r0 * 16 + t * 8,
             ((const u32x4*)stile)[t]);
    produce(2u * l + 1);
    // ================= gru =================
    f32x4 acc[6] = {};
    {
      const ushort* hr = sfrag(h_bf, kh, gg, row_a);
      b16x8 ha[8];
#pragma unroll
      for (int ks = 0; ks < 8; ++ks) ha[ks] = *(const b16x8*)(hr + ks * 8192);
#pragma unroll
      for (int ks = 0; ks < 8; ++ks)
#pragma unroll
        for (int g3 = 0; g3 < 3; ++g3)
          acc[3 + g3] = __builtin_amdgcn_mfma_f32_16x16x32_bf16(
              ha[ks], *(const b16x8*)(&Wlds[3 + g3][kh][ks][lane][0]),
              acc[3 + g3], 0, 0, 0);
    }
    await(2u * l + 1);
    {
      const ushort* xr = sfrag(a.x_s + (size_t)l * BH, kh, gg, row_a);
      b16x8 xa[8];
#pragma unroll
      for (int ks = 0; ks < 8; ++ks) xa[ks] = *(const b16x8*)(xr + ks * 8192);
#pragma unroll
      for (int ks = 0; ks < 8; ++ks)
#pragma unroll
        for (int g3 = 0; g3 < 3; ++g3)
          acc[g3] = __builtin_amdgcn_mfma_f32_16x16x32_bf16(
              xa[ks], *(const b16x8*)(&Wlds[g3][kh][ks][lane][0]),
              acc[g3], 0, 0, 0);
    }
    GRU_TAIL(a.dec_b_ih, a.dec_b_hh, a.H2_s + (size_t)l * BH,
             a.H2_rm + (size_t)l * BH);
    if (l != SL - 1) produce(2u * l + 2);
  }
}

// ---------------- one-pass register-resident log-softmax ----------------
__global__ __launch_bounds__(256) void lsesub_k(float* __restrict__ logits) {
  __shared__ float redm[4], reds[4];
  int row = blockIdx.x, t = threadIdx.x;
  float4* p = (float4*)(logits + (size_t)row * VOC);
  float4 v[10];
  float m = -1e30f, s = 0.f;
#pragma unroll
  for (int j = 0; j < 10; ++j) {
    int i = t + j * 256;
    if (i < 2500) {
      v[j] = p[i];
      float mx = fmaxf(fmaxf(v[j].x, v[j].y), fmaxf(v[j].z, v[j].w));
      if (mx > m) { s *= expf(m - mx); m = mx; }
      s += expf(v[j].x - m) + expf(v[j].y - m) + expf(v[j].z - m) + expf(v[j].w - m);
    }
  }
#pragma unroll
  for (int o = 32; o; o >>= 1) {
    float m2 = __shfl_xor(m, o, 64), s2 = __shfl_xor(s, o, 64);
    float mn = fmaxf(m, m2);
    s = s * expf(m - mn) + s2 * expf(m2 - mn);
    m = mn;
  }
  if ((t & 63) == 0) { redm[t >> 6] = m; reds[t >> 6] = s; }
  __syncthreads();
  float mf = fmaxf(fmaxf(redm[0], redm[1]), fmaxf(redm[2], redm[3]));
  float sf = reds[0] * expf(redm[0] - mf) + reds[1] * expf(redm[1] - mf) +
             reds[2] * expf(redm[2] - mf) + reds[3] * expf(redm[3] - mf);
  float z = mf + logf(sf);
#pragma unroll
  for (int j = 0; j < 10; ++j) {
    int i = t + j * 256;
    if (i < 2500) {
      v[j].x -= z; v[j].y -= z; v[j].z -= z; v[j].w -= z;
      p[i] = v[j];
    }
  }
}

extern "C" void kernel_launch(void* const* d_in, const int* in_sizes, int n_in,
                              void* d_out, int out_size, void* d_ws, size_t ws_size,
                              hipStream_t stream) {
  (void)in_sizes; (void)n_in; (void)out_size; (void)ws_size;
  const int* in_tok = (const int*)d_in[0];
  const int* tgt_tok = (const int*)d_in[1];
  const float* enc_embed = (const float*)d_in[2];
  const float* enc_w_ih = (const float*)d_in[3];
  const float* enc_w_hh = (const float*)d_in[4];
  const float* enc_b_ih = (const float*)d_in[5];
  const float* enc_b_hh = (const float*)d_in[6];
  const float* dec_embed = (const float*)d_in[7];
  const float* attn_w = (const float*)d_in[8];
  const float* attn_b = (const float*)d_in[9];
  const float* comb_w = (const float*)d_in[10];
  const float* comb_b = (const float*)d_in[11];
  const float* dec_w_ih = (const float*)d_in[12];
  const float* dec_w_hh = (const float*)d_in[13];
  const float* dec_b_ih = (const float*)d_in[14];
  const float* dec_b_hh = (const float*)d_in[15];
  const float* out_w = (const float*)d_in[16];
  const float* out_b = (const float*)d_in[17];
  float* out = (float*)d_out;

  char* ws = (char*)d_ws;
  size_t off = 0;
  auto carve = [&](size_t bytes) {
    void* p = ws + off;
    off += (bytes + 255) & ~(size_t)255;
    return p;
  };
  ushort* comb_w_bf  = (ushort*)carve(512 * 1024 * 2);
  ushort* attn_w_bf  = (ushort*)carve(32 * 1024 * 2);
  ushort* out_w_bf   = (ushort*)carve((size_t)VOC * HD * 2);
  ushort* enc_emb_bf = (ushort*)carve((size_t)SL * BA * HD * 2);
  ushort* dec_emb_bf = (ushort*)carve((size_t)SL * BA * HD * 2);
  float* attn_pre    = (float*)carve((size_t)SL * BA * 32 * 4);
  float* comb_pre    = (float*)carve((size_t)SL * BA * HD * 4);
  ushort* enc_outs_s = (ushort*)carve((size_t)SL * BA * HD * 2);
  ushort* enc_outs_rm= (ushort*)carve((size_t)SL * BA * HD * 2);
  ushort* encW       = (ushort*)carve((size_t)SL * BA * HD * 2);
  ushort* H2_s       = (ushort*)carve((size_t)SL * BA * HD * 2);
  ushort* H2_rm      = (ushort*)carve((size_t)SL * BA * HD * 2);
  ushort* x_s        = (ushort*)carve((size_t)SL * BA * HD * 2);
  float* Hc          = (float*)carve((size_t)BA * HD * 4);
  unsigned* fE_L2    = (unsigned*)carve(8 * 32 * 4 * 4);
  unsigned* fE_LLC   = (unsigned*)carve(8 * 32 * 16 * 4);
  unsigned* fD_L2    = (unsigned*)carve(8 * 32 * 4 * 4);
  unsigned* fD_LLC   = (unsigned*)carve(8 * 32 * 16 * 4);

  // ---- setup ----
  hipMemsetAsync(fE_L2, 0, (8 * 32 * 4 + 8 * 32 * 16) * 2 * 4, stream);
  cvt3_k<<<5544, 256, 0, stream>>>(out_w, out_w_bf, comb_w, comb_w_bf,
                                   attn_w, attn_w_bf);
  gather2_k<<<2 * SL * BA, 64, 0, stream>>>(enc_embed, dec_embed, in_tok,
                                            tgt_tok, enc_emb_bf, dec_emb_bf);

  // ---- merged decoder precomputes (attn_pre + comb_pre) ----
  gemm2_k<<<dim3(128, 9), 256, 0, stream>>>(dec_emb_bf, comb_w_bf, attn_w_bf,
                                            comb_b, attn_b, comb_pre, attn_pre);

  // ---- encoder (persistent, cooperative) ----
  EncArgs ea;
  ea.enc_emb_bf = enc_emb_bf;
  ea.enc_w_ih = enc_w_ih; ea.enc_w_hh = enc_w_hh;
  ea.enc_b_ih = enc_b_ih; ea.enc_b_hh = enc_b_hh;
  ea.enc_outs_s = enc_outs_s;
  ea.enc_outs_rm = enc_outs_rm;
  ea.Hc = Hc;
  ea.fL2 = fE_L2; ea.fLLC = fE_LLC;
  void* ekargs[] = { (void*)&ea };
  hipError_t ce = hipLaunchCooperativeKernel(enc_k, dim3(256), dim3(256),
                                             ekargs, 0, stream);
  if (ce != hipSuccess) enc_k<<<256, 256, 0, stream>>>(ea);

  // ---- encW = enc_outs @ comb_w[:,512:].T (interleaved bf16) ----
  gemmW_k<<<dim3(128, 8), 256, 0, stream>>>(enc_outs_rm, comb_w_bf, encW);

  // ---- decoder (persistent, cooperative) ----
  DecArgs da;
  da.dec_w_ih = dec_w_ih; da.dec_w_hh = dec_w_hh;
  da.dec_b_ih = dec_b_ih; da.dec_b_hh = dec_b_hh;
  da.attn_w_bf = attn_w_bf;
  da.attn_pre = attn_pre;
  da.comb_pre = comb_pre;
  da.enc_outs_s = enc_outs_s;
  da.encW = encW;
  da.Hc = Hc;
  da.H2_s = H2_s; da.H2_rm = H2_rm; da.x_s = x_s;
  da.fL2 = fD_L2; da.fLLC = fD_LLC;
  void* dkargs[] = { (void*)&da };
  ce = hipLaunchCooperativeKernel(dec_k, dim3(256), dim3(256),
                                  dkargs, 0, stream);
  if (ce != hipSuccess) dec_k<<<256, 256, 0, stream>>>(da);

  // ---- output projection (128x128 tile) + one-pass log_softmax ----
  gemmbig_k<<<dim3(64, 79), 256, 0, stream>>>(H2_rm, out_w_bf, VOC,
                                              out_b, out, VOC);
  lsesub_k<<<SL * BA, 256, 0, stream>>>(out);
}